// Round 3
// baseline (189.007 us; speedup 1.0000x reference)
//
#include <hip/hip_runtime.h>
#include <math.h>

#define KDIM 128
#define TLEN 512
#define BATCH 16
#define CH_L 16
#define NCH 32           // chunks per batch (replay)
#define NMAT 31          // chunk matrices: chunk c covers t in [16c+1, 16c+16]

typedef _Float16 half8 __attribute__((ext_vector_type(8)));
typedef _Float16 half4 __attribute__((ext_vector_type(4)));
typedef _Float16 half2t __attribute__((ext_vector_type(2)));
typedef float floatx4 __attribute__((ext_vector_type(4)));

#if defined(__has_builtin)
#if __has_builtin(__builtin_amdgcn_fdot2)
#define HAVE_FDOT2 1
#endif
#endif

static __device__ __forceinline__ float dot2f(half2t a, half2t b, float c) {
#ifdef HAVE_FDOT2
    return __builtin_amdgcn_fdot2(a, b, c, false);
#else
    return fmaf((float)a[0], (float)b[0], fmaf((float)a[1], (float)b[1], c));
#endif
}

// acc += dot(packed-f16 w (4 VGPRs = 8 halfs), half8 v)
static __device__ __forceinline__ float dot8(const half8 v, const float4 w, float acc) {
    const uint4 r = __builtin_bit_cast(uint4, v);
    acc = dot2f(__builtin_bit_cast(half2t, w.x), __builtin_bit_cast(half2t, r.x), acc);
    acc = dot2f(__builtin_bit_cast(half2t, w.y), __builtin_bit_cast(half2t, r.y), acc);
    acc = dot2f(__builtin_bit_cast(half2t, w.z), __builtin_bit_cast(half2t, r.z), acc);
    acc = dot2f(__builtin_bit_cast(half2t, w.w), __builtin_bit_cast(half2t, r.w), acc);
    return acc;
}

// async global->LDS, 16 B per lane; LDS dest = wave-uniform base + lane*16
static __device__ __forceinline__ void gload_lds16(const _Float16* g, _Float16* l) {
    __builtin_amdgcn_global_load_lds(
        (const __attribute__((address_space(1))) void*)g,
        (__attribute__((address_space(3))) void*)l, 16, 0, 0);
}

// ---------------- workspace layout (bytes) ----------------
// PST : f16 [BATCH][NMAT] chunk products; scan layout: 16B unit u = (2K+h)*64+l
//       holds P[enter=K*8+e][exit=2l+h]
// SVEC: f32 [BATCH][NMAT][128] per-enter-column log scales
#define WSN_PST   0
#define WSN_SVEC  16252928
#define WSN_AENT  16506880
#define WSN_NEED  16769024

// Frag conventions (validated):
//  A-frag tile(mt,kt): lane(quad,lm) holds A[mt*16+lm][kt*32+quad*8 .. +8]
//  B-frag tile(kt,nt): lane(quad,lm) holds B[kt*32+quad*8 .. +8][nt*16+lm]
//  C/D  tile(mt,nt):   lane(quad,lm) reg q = C[mt*16+quad*4+q][nt*16+lm]
//
// ============ kernel 1: 2-wave column-parallel chunk products ================
// R2 post-mortem: VGPR_Count=128 proved the A-hoist failed (Af alone is 128
// regs); the 256-thread occupancy heuristic + in-loop asm "memory" clobbers
// forced per-iteration LDS re-reads of the loop-invariant F. Fixes here:
//  * 128-thread blocks (2 waves x 64 columns): per-CU F-traffic halves even
//    if the hoist fails; small-block kernels escape the ~128-reg cap.
//  * __launch_bounds__(128,1): budget 512 regs; steady live ~205.
//  * NO asm memory clobbers: plain LDS accesses alias within each __shared__
//    array, so hipcc orders them and inserts its own lgkmcnt.
//  * B-layout stride 144 halfs (read conflicts 8-way -> 4-way); final
//    iteration writes the SAME B-layout (no T-layout: it used to clobber
//    other passes' B-regions; epilogue gathers with 2-lane/bank scalar reads).
__global__ __launch_bounds__(128, 1) void crf_chunkcols3(
    const float* __restrict__ trans, const float* __restrict__ em,
    _Float16* __restrict__ Pst, float* __restrict__ Svec)
{
    const int c = blockIdx.x;     // 0..NMAT-1
    const int b = blockIdx.y;
    const int tid = threadIdx.x;
    const int w = tid >> 6, lane = tid & 63;
    const int quad = lane >> 4, lm = lane & 15;

    // F[m][k] = exp(trans[k][m]); row stride 136 halfs
    __shared__ __align__(16) _Float16 Flds[128 * 136];   // 34,816 B
    // Per-wave running product, B-layout [n_local][k], stride 144 halfs
    __shared__ __align__(16) _Float16 Wscr[2][9216];     // 36,864 B
    __shared__ __align__(16) float gAll[16 * KDIM];      // 8,192 B
    // total 79,872 B -> 2 blocks/CU

    const int t0 = c * CH_L + 1;
    const float* emb = em + (size_t)b * TLEN * KDIM;

    // ---- stage F (transposed exp(trans)); row m = tid ----
    {
        const int m = tid;
        #pragma unroll
        for (int kk = 0; kk < 16; ++kk) {
            const int k0 = kk * 8;
            half8 o;
            #pragma unroll
            for (int j = 0; j < 8; ++j)
                o[j] = (_Float16)__expf(trans[(k0 + j) * KDIM + m]);
            *(half8*)&Flds[m * 136 + k0] = o;
        }
    }
    // ---- stage g = exp(em[t0 .. t0+15]) : 4 float4 per thread ----
    #pragma unroll
    for (int s = 0; s < 4; ++s) {
        const int i4 = (tid + s * 128) * 4;
        const float4 e = *(const float4*)&emb[t0 * KDIM + i4];
        float4 gv;
        gv.x = __expf(e.x); gv.y = __expf(e.y); gv.z = __expf(e.z); gv.w = __expf(e.w);
        *(float4*)&gAll[i4] = gv;
    }
    __syncthreads();                                     // the ONLY barrier

    _Float16* Wb = Wscr[w];
    float sc[4];

    // ---- init B0[k][n] = exp(trans[n][k]) * g0[k], column-normalized ----
    #pragma unroll
    for (int nt = 0; nt < 4; ++nt) {
        float tv[4][8];
        float cm = 0.f;
        const int n = 64 * w + nt * 16 + lm;
        #pragma unroll
        for (int kt = 0; kt < 4; ++kt) {
            const int r0 = kt * 32 + quad * 8;
            const float4 ga = *(const float4*)&gAll[r0];
            const float4 gb = *(const float4*)&gAll[r0 + 4];
            const float gg[8] = {ga.x, ga.y, ga.z, ga.w, gb.x, gb.y, gb.z, gb.w};
            const float4 ta = *(const float4*)&trans[(size_t)n * KDIM + r0];
            const float4 tb = *(const float4*)&trans[(size_t)n * KDIM + r0 + 4];
            const float tt[8] = {ta.x, ta.y, ta.z, ta.w, tb.x, tb.y, tb.z, tb.w};
            #pragma unroll
            for (int j = 0; j < 8; ++j) {
                const float v = __expf(tt[j]) * gg[j];
                tv[kt][j] = v;
                cm = fmaxf(cm, v);
            }
        }
        cm = fmaxf(cm, __shfl_xor(cm, 16));
        cm = fmaxf(cm, __shfl_xor(cm, 32));
        const float ri = 1.0f / cm;
        sc[nt] = __logf(cm);
        #pragma unroll
        for (int kt = 0; kt < 4; ++kt) {
            half8 o;
            #pragma unroll
            for (int j = 0; j < 8; ++j) o[j] = (_Float16)(tv[kt][j] * ri);
            *(half8*)&Wb[(nt * 16 + lm) * 144 + kt * 32 + quad * 8] = o;
        }
    }

    // ---- hoist all A fragments (one-time 32 ds_read_b128; 128 VGPR) ----
    half8 Af[8][4];
    #pragma unroll
    for (int mt = 0; mt < 8; ++mt)
        #pragma unroll
        for (int kt = 0; kt < 4; ++kt)
            Af[mt][kt] = *(const half8*)&Flds[lm * 136 + quad * 8 + mt * 2176 + kt * 32];

    const floatx4 z4 = {0.f, 0.f, 0.f, 0.f};
    for (int it = 1; it < 16; ++it) {
        #pragma unroll
        for (int nt = 0; nt < 4; ++nt) {
            // load this pass's B frags (previous iteration's relayout, region nt)
            half8 Bf[4];
            #pragma unroll
            for (int kt = 0; kt < 4; ++kt)
                Bf[kt] = *(const half8*)&Wb[(nt * 16 + lm) * 144 + kt * 32 + quad * 8];

            floatx4 acc[8];
            #pragma unroll
            for (int mt = 0; mt < 8; ++mt)
                acc[mt] = __builtin_amdgcn_mfma_f32_16x16x32_f16(Af[mt][0], Bf[0], z4, 0, 0, 0);
            #pragma unroll
            for (int kt = 1; kt < 4; ++kt)
                #pragma unroll
                for (int mt = 0; mt < 8; ++mt)
                    acc[mt] = __builtin_amdgcn_mfma_f32_16x16x32_f16(Af[mt][kt], Bf[kt], acc[mt], 0, 0, 0);

            // row-scale by g_t, per-column max (wave-local)
            const float* g = &gAll[it * KDIM];
            float cm = 0.f;
            #pragma unroll
            for (int mt = 0; mt < 8; ++mt) {
                const float4 gv = *(const float4*)&g[mt * 16 + quad * 4];  // quad-broadcast
                floatx4 v = acc[mt];
                v.x *= gv.x; v.y *= gv.y; v.z *= gv.z; v.w *= gv.w;
                acc[mt] = v;
                cm = fmaxf(cm, fmaxf(fmaxf(v.x, v.y), fmaxf(v.z, v.w)));
            }
            cm = fmaxf(cm, __shfl_xor(cm, 16));
            cm = fmaxf(cm, __shfl_xor(cm, 32));
            const float ri = 1.0f / cm;
            sc[nt] += __logf(cm);

            // C -> B relayout into OWN region nt (read-before-write same pass;
            // same-wave DS order keeps iteration dependences correct)
            #pragma unroll
            for (int mt = 0; mt < 8; ++mt) {
                const floatx4 v = acc[mt];
                half4 o;
                o[0] = (_Float16)(v.x * ri);
                o[1] = (_Float16)(v.y * ri);
                o[2] = (_Float16)(v.z * ri);
                o[3] = (_Float16)(v.w * ri);
                *(half4*)&Wb[(nt * 16 + lm) * 144 + mt * 16 + quad * 4] = o;
            }
        }
    }

    // ---- epilogue: gather scan-layout 16B units from B-layout ----
    // unit u=(2K+h)*64+l holds P[enter=K*8+e][exit=2l+h] = Wb[(enter_l)*144 + exit]
    _Float16* Pc = Pst + ((size_t)(b * NMAT + c)) * 16384;
    #pragma unroll
    for (int Kl = 0; Kl < 8; ++Kl)
        #pragma unroll
        for (int h = 0; h < 2; ++h) {
            half8 v;
            #pragma unroll
            for (int e = 0; e < 8; ++e)
                v[e] = Wb[(Kl * 8 + e) * 144 + 2 * lane + h];
            const int u = (2 * (8 * w + Kl) + h) * 64 + lane;
            *(half8*)&Pc[(size_t)u * 8] = v;
        }
    if (quad == 0) {
        float* sp = Svec + ((size_t)(b * NMAT + c)) * KDIM + 64 * w;
        #pragma unroll
        for (int nt = 0; nt < 4; ++nt) sp[nt * 16 + lm] = sc[nt];
    }
}

// ============ kernel 2: scan, triple-buffered DMA with counted vmcnt ==========
// 3 x 32KB buffers; steady-state wait is vmcnt(32) (chunk c done, chunk c+1's
// 32 loads still in flight), chunk c+2 issued before compute.
// p' = exp(lq + s - M), M = wave max -> p' <= 1 (f16-safe).
__global__ __launch_bounds__(64, 1) void crf_scanw4(
    const float* __restrict__ em, const _Float16* __restrict__ Pst,
    const float* __restrict__ Svec, float* __restrict__ aEnter)
{
    const int b = blockIdx.x;
    const int lane = threadIdx.x;
    const int j0 = 2 * lane;

    __shared__ __align__(16) _Float16 Pbuf[3][16384];  // 96 KB triple buffer
    __shared__ __align__(16) _Float16 pbuf[KDIM];

    const _Float16* Pb = Pst + (size_t)b * NMAT * 16384;
    const float* svb = Svec + (size_t)b * NMAT * KDIM;
    float* aeb = aEnter + (size_t)b * NCH * KDIM;

    // prologue: issue chunks 0 and 1
    #pragma unroll
    for (int i = 0; i < 32; ++i)
        gload_lds16(Pb + i * 512 + lane * 8, &Pbuf[0][i * 512]);
    #pragma unroll
    for (int i = 0; i < 32; ++i)
        gload_lds16(Pb + 16384 + i * 512 + lane * 8, &Pbuf[1][i * 512]);

    float2 a0 = *(const float2*)&em[(size_t)b * TLEN * KDIM + j0];
    float mx = fmaxf(a0.x, a0.y);
    #pragma unroll
    for (int o = 32; o; o >>= 1) mx = fmaxf(mx, __shfl_xor(mx, o));
    *(float2*)&aeb[j0] = a0;
    float lq0 = a0.x - mx, lq1 = a0.y - mx;
    float L = mx;
    float2 sv = *(const float2*)&svb[j0];

    int cb = 0;
    for (int c = 0; c < NMAT; ++c) {
        // chunk c complete: all but the most recent 32 loads (chunk c+1) retired
        if (c + 1 < NMAT) {
            asm volatile("s_waitcnt vmcnt(32)" ::: "memory");
        } else {
            asm volatile("s_waitcnt vmcnt(0)" ::: "memory");
        }

        // issue DMA for chunk c+2 (two iterations of slack)
        if (c + 2 < NMAT) {
            const _Float16* src = Pb + (size_t)(c + 2) * 16384;
            _Float16* dst = &Pbuf[(cb + 2) % 3][0];
            #pragma unroll
            for (int i = 0; i < 32; ++i)
                gload_lds16(src + i * 512 + lane * 8, &dst[i * 512]);
        }

        // fold per-column scales into p; normalize by wave max
        const float v0 = lq0 + sv.x, v1 = lq1 + sv.y;
        float M = fmaxf(v0, v1);
        #pragma unroll
        for (int o = 32; o; o >>= 1) M = fmaxf(M, __shfl_xor(M, o));
        half2t p2;
        p2[0] = (_Float16)__expf(v0 - M);
        p2[1] = (_Float16)__expf(v1 - M);
        ((half2t*)pbuf)[lane] = p2;
        if (c + 1 < NMAT) sv = *(const float2*)&svb[(size_t)(c + 1) * KDIM + j0];

        // ---- matvec: q_j = sum_k p'_k P~[k][j], j = 2l, 2l+1 ----
        const _Float16* Pcur = &Pbuf[cb][0];
        float q0 = 0.f, q1 = 0.f;
        #pragma unroll
        for (int K = 0; K < 16; ++K) {
            const float4 wv = *(const float4*)&pbuf[K * 8];
            const half8 c0 = *(const half8*)&Pcur[((2 * K + 0) * 64 + lane) * 8];
            const half8 c1 = *(const half8*)&Pcur[((2 * K + 1) * 64 + lane) * 8];
            q0 = dot8(c0, wv, q0);
            q1 = dot8(c1, wv, q1);
        }

        const float base = L + M;
        const float lg0 = __logf(q0), lg1 = __logf(q1);
        float2 st;
        st.x = base + lg0;
        st.y = base + lg1;
        *(float2*)&aeb[(size_t)(c + 1) * KDIM + j0] = st;
        lq0 = lg0;
        lq1 = lg1;
        L = base;
        cb = (cb + 1) % 3;
    }
}

// ================= kernel 3: replayw — one wave per (chunk,batch) =============
__global__ __launch_bounds__(64, 1) void crf_replayw(
    const float* __restrict__ trans, const float* __restrict__ em,
    const int* __restrict__ seq_lens, const float* __restrict__ aEnter,
    float* __restrict__ alpha, float* __restrict__ logZ)
{
    const int c = blockIdx.x, b = blockIdx.y;
    const int l = threadIdx.x;

    __shared__ __align__(16) _Float16 pbuf[KDIM];

    half2t Ea[64], Eb[64];
    #pragma unroll
    for (int t2 = 0; t2 < 64; ++t2) {
        const float* r0 = &trans[(2 * t2) * KDIM];
        const float* r1 = &trans[(2 * t2 + 1) * KDIM];
        half2t ea, eb;
        ea[0] = (_Float16)__expf(r0[l]);
        ea[1] = (_Float16)__expf(r1[l]);
        eb[0] = (_Float16)__expf(r0[l + 64]);
        eb[1] = (_Float16)__expf(r1[l + 64]);
        Ea[t2] = ea;
        Eb[t2] = eb;
    }

    const int len = seq_lens[b];
    const float* emb = em + (size_t)b * TLEN * KDIM;
    float* outb = alpha + (size_t)b * TLEN * KDIM;
    const float* ae = aEnter + ((size_t)b * NCH + c) * KDIM;

    float a0 = ae[l], a1 = ae[l + 64];
    if (c == 0) {
        a0 = emb[l];
        a1 = emb[l + 64];
    }
    float mx = fmaxf(a0, a1);
    #pragma unroll
    for (int o = 32; o; o >>= 1) mx = fmaxf(mx, __shfl_xor(mx, o));
    float L = mx;
    pbuf[l]      = (_Float16)__expf(a0 - L);
    pbuf[l + 64] = (_Float16)__expf(a1 - L);

    float la0 = 0.f, la1 = -INFINITY;
    if (c == 0) {
        outb[l] = a0;
        outb[l + 64] = a1;
        if (len == 1) { la0 = a0; la1 = a1; }
    }

    const int t_begin = c * CH_L + 1;
    const int t_end = (c == NCH - 1) ? (TLEN - 1) : (c * CH_L + CH_L);

    float e0 = emb[t_begin * KDIM + l];
    float e1 = emb[t_begin * KDIM + l + 64];

    for (int t = t_begin; t <= t_end; ++t) {
        float n0 = 0.f, n1 = 0.f;
        if (t < t_end) {
            n0 = emb[(t + 1) * KDIM + l];
            n1 = emb[(t + 1) * KDIM + l + 64];
        }

        float q0 = 0.f, q1 = 0.f;
        #pragma unroll
        for (int s = 0; s < 16; ++s) {
            const float4 w = *(const float4*)&pbuf[s * 8];
            const half2t p0 = __builtin_bit_cast(half2t, w.x);
            const half2t p1 = __builtin_bit_cast(half2t, w.y);
            const half2t p2 = __builtin_bit_cast(half2t, w.z);
            const half2t p3 = __builtin_bit_cast(half2t, w.w);
            q0 = dot2f(p0, Ea[4 * s + 0], q0);
            q0 = dot2f(p1, Ea[4 * s + 1], q0);
            q0 = dot2f(p2, Ea[4 * s + 2], q0);
            q0 = dot2f(p3, Ea[4 * s + 3], q0);
            q1 = dot2f(p0, Eb[4 * s + 0], q1);
            q1 = dot2f(p1, Eb[4 * s + 1], q1);
            q1 = dot2f(p2, Eb[4 * s + 2], q1);
            q1 = dot2f(p3, Eb[4 * s + 3], q1);
        }

        const float A0 = e0 + L + __logf(q0);
        const float A1 = e1 + L + __logf(q1);
        outb[t * KDIM + l] = A0;
        outb[t * KDIM + l + 64] = A1;
        if (t == len - 1) { la0 = A0; la1 = A1; }

        const float sigma = __shfl(q0, 0);
        const float ri = 1.0f / sigma;
        pbuf[l]      = (_Float16)(q0 * ri * __expf(e0));
        pbuf[l + 64] = (_Float16)(q1 * ri * __expf(e1));
        L += __logf(sigma);
        e0 = n0; e1 = n1;
    }

    const bool blockowns = (len == 1) ? (c == 0) : (((len - 2) >> 4) == c);
    if (blockowns) {
        float m2 = fmaxf(la0, la1);
        #pragma unroll
        for (int o = 32; o; o >>= 1) m2 = fmaxf(m2, __shfl_xor(m2, o));
        float e = __expf(la0 - m2) + __expf(la1 - m2);
        #pragma unroll
        for (int o = 32; o; o >>= 1) e += __shfl_xor(e, o);
        if (l == 0) logZ[b] = m2 + __logf(e);
    }
}

// ================= fallback (proven R1 kernel) for small ws =================
__global__ __launch_bounds__(256) void crf_forward_fallback(
    const float* __restrict__ trans, const float* __restrict__ em,
    const int* __restrict__ seq_lens, float* __restrict__ alpha_out,
    float* __restrict__ logZ_out)
{
    const int b = blockIdx.x;
    const int tid = threadIdx.x;
    const int j = tid & (KDIM - 1);
    const int h = tid >> 7;

    __shared__ __align__(16) float p_lds[KDIM];
    __shared__ float part[KDIM];
    __shared__ float red[8];

    float Ereg[64];
    #pragma unroll
    for (int k = 0; k < 64; ++k) Ereg[k] = __expf(trans[(h * 64 + k) * KDIM + j]);

    const int len = seq_lens[b];
    const float* emb = em + (size_t)b * TLEN * KDIM;
    float* outb = alpha_out + (size_t)b * TLEN * KDIM;

    float a = 0.f, last_a = 0.f;
    if (h == 0) {
        a = emb[j];
        outb[j] = a;
        if (len == 1) last_a = a;
    }
    for (int t = 1; t < TLEN; ++t) {
        {
            float v = (h == 0) ? a : -INFINITY;
            #pragma unroll
            for (int o = 32; o >= 1; o >>= 1) v = fmaxf(v, __shfl_xor(v, o));
            if ((tid & 63) == 0) red[tid >> 6] = v;
        }
        __syncthreads();
        const float m = fmaxf(red[0], red[1]);
        if (h == 0) p_lds[j] = __expf(a - m);
        __syncthreads();
        float em_t = 0.f;
        if (h == 0) em_t = emb[t * KDIM + j];
        float acc0 = 0.f, acc1 = 0.f, acc2 = 0.f, acc3 = 0.f;
        const float4* p4 = (const float4*)(p_lds + h * 64);
        #pragma unroll
        for (int k4 = 0; k4 < 16; ++k4) {
            float4 pv = p4[k4];
            acc0 = fmaf(pv.x, Ereg[4 * k4 + 0], acc0);
            acc1 = fmaf(pv.y, Ereg[4 * k4 + 1], acc1);
            acc2 = fmaf(pv.z, Ereg[4 * k4 + 2], acc2);
            acc3 = fmaf(pv.w, Ereg[4 * k4 + 3], acc3);
        }
        const float acc = (acc0 + acc1) + (acc2 + acc3);
        if (h == 1) part[j] = acc;
        __syncthreads();
        if (h == 0) {
            const float q = acc + part[j];
            a = em_t + m + __logf(q);
            outb[t * KDIM + j] = a;
            if (t == len - 1) last_a = a;
        }
    }
    {
        float v = (h == 0) ? last_a : -INFINITY;
        #pragma unroll
        for (int o = 32; o >= 1; o >>= 1) v = fmaxf(v, __shfl_xor(v, o));
        if ((tid & 63) == 0) red[tid >> 6] = v;
    }
    __syncthreads();
    const float m2 = fmaxf(red[0], red[1]);
    float e = (h == 0) ? __expf(last_a - m2) : 0.f;
    #pragma unroll
    for (int o = 32; o >= 1; o >>= 1) e += __shfl_xor(e, o);
    if ((tid & 63) == 0) red[4 + (tid >> 6)] = e;
    __syncthreads();
    if (tid == 0) logZ_out[b] = m2 + logf(red[4] + red[5]);
}

extern "C" void kernel_launch(void* const* d_in, const int* in_sizes, int n_in,
                              void* d_out, int out_size, void* d_ws, size_t ws_size,
                              hipStream_t stream) {
    const float* trans    = (const float*)d_in[0];   // K*K
    const float* em       = (const float*)d_in[1];   // B*T*K
    const int*   seq_lens = (const int*)d_in[2];     // B

    float* alpha_out = (float*)d_out;                            // B*T*K
    float* logZ_out  = alpha_out + (size_t)BATCH * TLEN * KDIM;  // B

    char* ws = (char*)d_ws;

    if (ws_size >= (size_t)WSN_NEED) {
        _Float16* Pst  = (_Float16*)(ws + WSN_PST);
        float*    Svec = (float*)(ws + WSN_SVEC);
        float*    aEnt = (float*)(ws + WSN_AENT);
        crf_chunkcols3<<<dim3(NMAT, BATCH), 128, 0, stream>>>(trans, em, Pst, Svec);
        crf_scanw4<<<BATCH, 64, 0, stream>>>(em, Pst, Svec, aEnt);
        crf_replayw<<<dim3(NCH, BATCH), 64, 0, stream>>>(trans, em, seq_lens, aEnt,
                                                         alpha_out, logZ_out);
    } else {
        crf_forward_fallback<<<BATCH, 256, 0, stream>>>(trans, em, seq_lens,
                                                        alpha_out, logZ_out);
    }
}